// Round 1
// baseline (306.600 us; speedup 1.0000x reference)
//
#include <hip/hip_runtime.h>
#include <hip/hip_bf16.h>

#define B_  4
#define T_  2048
#define D_  768
#define H_  12
#define DH_ 64
#define FF_ 3072

typedef __attribute__((ext_vector_type(8))) short bf16x8;
typedef __attribute__((ext_vector_type(4))) float f32x4;
typedef __attribute__((ext_vector_type(4))) unsigned short us4;

#define MFMA16(a, b, c) __builtin_amdgcn_mfma_f32_16x16x32_bf16((a), (b), (c), 0, 0, 0)

__device__ __forceinline__ unsigned short f2bf(float f) {
    union { float f; unsigned u; } v; v.f = f;
    unsigned r = v.u + 0x7fffu + ((v.u >> 16) & 1u);
    return (unsigned short)(r >> 16);
}

// async global->LDS, 16B per lane. LDS dest must be wave-uniform; HW adds lane*16.
__device__ __forceinline__ void gload_lds16(const unsigned short* gp, unsigned short* lp) {
    __builtin_amdgcn_global_load_lds(
        (const __attribute__((address_space(1))) unsigned int*)gp,
        (__attribute__((address_space(3))) unsigned int*)lp,
        16, 0, 0);
}

// ---------------- weight convert + transpose: src[K][N] f32 -> dst[N][K] bf16 ----------
__global__ __launch_bounds__(256) void tcvt_kernel(
    const float* __restrict__ src, unsigned short* __restrict__ dst, int K, int N)
{
    __shared__ float tile[32][33];
    const int bx = blockIdx.x * 32;  // N dim
    const int by = blockIdx.y * 32;  // K dim
    const int tx = threadIdx.x, ty = threadIdx.y;  // 32 x 8
#pragma unroll
    for (int i = 0; i < 32; i += 8)
        tile[ty + i][tx] = src[(size_t)(by + ty + i) * N + bx + tx];
    __syncthreads();
#pragma unroll
    for (int i = 0; i < 32; i += 8)
        dst[(size_t)(bx + ty + i) * K + by + tx] = f2bf(tile[tx][ty + i]);
}

// ---------------- LayerNorm: fp32 in -> bf16 out ----------------
__global__ __launch_bounds__(256) void ln_kernel(
    const float* __restrict__ x, const float* __restrict__ g,
    const float* __restrict__ be, unsigned short* __restrict__ out)
{
    const int row = blockIdx.x;
    const int t = threadIdx.x;
    const float* xr = x + (size_t)row * D_;
    float v0 = xr[t], v1 = xr[t + 256], v2 = xr[t + 512];
    float s = v0 + v1 + v2;
    float s2 = v0 * v0 + v1 * v1 + v2 * v2;
#pragma unroll
    for (int o = 1; o < 64; o <<= 1) {
        s  += __shfl_xor(s,  o);
        s2 += __shfl_xor(s2, o);
    }
    __shared__ float rs[4], rq[4];
    const int wave = t >> 6;
    if ((t & 63) == 0) { rs[wave] = s; rq[wave] = s2; }
    __syncthreads();
    s  = rs[0] + rs[1] + rs[2] + rs[3];
    s2 = rq[0] + rq[1] + rq[2] + rq[3];
    const float mu = s * (1.0f / D_);
    const float var = s2 * (1.0f / D_) - mu * mu;
    const float rstd = rsqrtf(var + 1e-5f);
    unsigned short* orow = out + (size_t)row * D_;
    orow[t]       = f2bf((v0 - mu) * rstd * g[t]       + be[t]);
    orow[t + 256] = f2bf((v1 - mu) * rstd * g[t + 256] + be[t + 256]);
    orow[t + 512] = f2bf((v2 - mu) * rstd * g[t + 512] + be[t + 512]);
}

// ---------------- GEMM: C[M][N] = A[M][K] * Bt[N][K]^T + bias ----------------
// MODE 0: bf16 out [M][N]
// MODE 1: bf16 out transposed per batch: out[b][n][t]  (for V)
// MODE 2: gelu(exact) -> bf16 out [M][N]
// MODE 3: fp32 out [M][N] = acc + bias + resid
template<int MODE>
__global__ __launch_bounds__(256) void gemm_bf16(
    const unsigned short* __restrict__ A,
    const unsigned short* __restrict__ Bt,
    const float* __restrict__ bias,
    const float* __restrict__ resid,
    void* __restrict__ outp,
    int M, int N, int K)
{
    __shared__ __align__(16) unsigned short As[128 * 32];
    __shared__ __align__(16) unsigned short Bs[128 * 32];
    const int tid = threadIdx.x;
    const int wave = tid >> 6;
    const int lane = tid & 63;
    const int m0 = blockIdx.x * 128;
    const int n0 = blockIdx.y * 128;
    const int wr = wave >> 1;
    const int wc = wave & 1;

    f32x4 zero4 = {0.0f, 0.0f, 0.0f, 0.0f};
    f32x4 acc[4][4];
#pragma unroll
    for (int i = 0; i < 4; ++i)
#pragma unroll
        for (int j = 0; j < 4; ++j) acc[i][j] = zero4;

    // staging: 8 chunks of 1KB per 8KB tile; wave handles chunks {2w, 2w+1}
    const int ch0 = wave * 2;
    const int srow = lane >> 2;          // 0..15
    const int scol = (lane & 3) * 8;     // 0,8,16,24
    const size_t a_base0 = (size_t)(m0 + ch0 * 16 + srow) * K + scol;
    const size_t a_base1 = a_base0 + (size_t)16 * K;
    const size_t b_base0 = (size_t)(n0 + ch0 * 16 + srow) * K + scol;
    const size_t b_base1 = b_base0 + (size_t)16 * K;
    unsigned short* As0 = As + ch0 * 512;
    unsigned short* Bs0 = Bs + ch0 * 512;

    const int nk = K >> 5;
    for (int kt = 0; kt < nk; ++kt) {
        const int k0 = kt << 5;
        __syncthreads();
        gload_lds16(A  + a_base0 + k0, As0);
        gload_lds16(A  + a_base1 + k0, As0 + 512);
        gload_lds16(Bt + b_base0 + k0, Bs0);
        gload_lds16(Bt + b_base1 + k0, Bs0 + 512);
        __syncthreads();
        bf16x8 afr[4], bfr[4];
#pragma unroll
        for (int mm = 0; mm < 4; ++mm)
            afr[mm] = *(const bf16x8*)(As + (wr * 64 + mm * 16 + (lane & 15)) * 32 + (lane >> 4) * 8);
#pragma unroll
        for (int nn = 0; nn < 4; ++nn)
            bfr[nn] = *(const bf16x8*)(Bs + (wc * 64 + nn * 16 + (lane & 15)) * 32 + (lane >> 4) * 8);
#pragma unroll
        for (int mm = 0; mm < 4; ++mm)
#pragma unroll
            for (int nn = 0; nn < 4; ++nn)
                acc[mm][nn] = MFMA16(afr[mm], bfr[nn], acc[mm][nn]);
    }

    const int lc = lane & 15;
    const int lr = (lane >> 4) * 4;
#pragma unroll
    for (int mm = 0; mm < 4; ++mm) {
        const int gm0 = m0 + wr * 64 + mm * 16 + lr;
#pragma unroll
        for (int nn = 0; nn < 4; ++nn) {
            const int gn = n0 + wc * 64 + nn * 16 + lc;
            const float bv = bias[gn];
            if (MODE == 1) {
                const int b = gm0 / T_;
                const int tl = gm0 - b * T_;
                us4 pk;
#pragma unroll
                for (int r = 0; r < 4; ++r) pk[r] = f2bf(acc[mm][nn][r] + bv);
                *(us4*)((unsigned short*)outp + ((size_t)(b * D_ + gn)) * T_ + tl) = pk;
            } else {
#pragma unroll
                for (int r = 0; r < 4; ++r) {
                    const int gm = gm0 + r;
                    float v = acc[mm][nn][r] + bv;
                    if (MODE == 0) {
                        ((unsigned short*)outp)[(size_t)gm * N + gn] = f2bf(v);
                    } else if (MODE == 2) {
                        v = 0.5f * v * (1.0f + erff(v * 0.70710678118654752f));
                        ((unsigned short*)outp)[(size_t)gm * N + gn] = f2bf(v);
                    } else if (MODE == 3) {
                        ((float*)outp)[(size_t)gm * N + gn] = v + resid[(size_t)gm * N + gn];
                    }
                }
            }
        }
    }
}

// ---------------- banded flash attention ----------------
// block = 256 threads (4 waves), handles (b, h, 64-query tile)
// K/V window = [t0, t1), KW <= 192
__global__ __launch_bounds__(256) void attn_kernel(
    const unsigned short* __restrict__ Q,    // [B*T][768]
    const unsigned short* __restrict__ Kg,   // [B*T][768]
    const unsigned short* __restrict__ Vt,   // [B][768][T]
    unsigned short* __restrict__ ctx)        // [B*T][768]
{
    __shared__ __align__(16) unsigned short Qs[64][72];
    __shared__ __align__(16) unsigned short KP[192 * 72];   // Ks[192][72], later Ps[64][200]
    __shared__ __align__(16) unsigned short Vts[64][200];

    const int tid = threadIdx.x;
    const int lane = tid & 63;
    const int w = tid >> 6;
    const int bid = blockIdx.x;
    const int qt = bid & 31;
    const int h = (bid >> 5) % H_;
    const int b = bid / (32 * H_);
    const int qs = qt * 64;
    const int t0 = qs >= 64 ? qs - 64 : 0;
    const int t1 = (qs + 128 < T_) ? qs + 128 : T_;
    const int KW = t1 - t0;

    // stage Q (64 rows x 64 cols)
    for (int s = tid; s < 512; s += 256) {
        const int r = s >> 3, c8 = (s & 7) << 3;
        *(uint4*)&Qs[r][c8] =
            *(const uint4*)&Q[((size_t)(b * T_ + qs + r)) * D_ + h * DH_ + c8];
    }
    // stage K (192 rows x 64), zero-filled beyond window
    unsigned short* Ks = KP;
    for (int s = tid; s < 1536; s += 256) {
        const int r = s >> 3, c8 = (s & 7) << 3;
        uint4 val = {0, 0, 0, 0};
        if (r < KW)
            val = *(const uint4*)&Kg[((size_t)(b * T_ + t0 + r)) * D_ + h * DH_ + c8];
        *(uint4*)&Ks[r * 72 + c8] = val;
    }
    // stage V^T (64 dh-rows x 192 key-cols), zero-filled beyond window
    for (int s = tid; s < 1536; s += 256) {
        const int r = s / 24, c8 = (s % 24) << 3;
        uint4 val = {0, 0, 0, 0};
        if (c8 < KW)
            val = *(const uint4*)&Vt[((size_t)((b * H_ + h) * DH_ + r)) * T_ + t0 + c8];
        *(uint4*)&Vts[r][c8] = val;
    }
    __syncthreads();

    // S = Q K^T : per wave 16 q-rows x 192 keys, 12 col-frags, K=64 (2 ksteps)
    f32x4 zero4 = {0.0f, 0.0f, 0.0f, 0.0f};
    f32x4 sa[12];
#pragma unroll
    for (int i = 0; i < 12; ++i) sa[i] = zero4;
#pragma unroll
    for (int ks = 0; ks < 2; ++ks) {
        const bf16x8 aq = *(const bf16x8*)&Qs[w * 16 + (lane & 15)][ks * 32 + (lane >> 4) * 8];
#pragma unroll
        for (int cf = 0; cf < 12; ++cf) {
            const bf16x8 bk = *(const bf16x8*)&Ks[(cf * 16 + (lane & 15)) * 72 + ks * 32 + (lane >> 4) * 8];
            sa[cf] = MFMA16(aq, bk, sa[cf]);
        }
    }
    __syncthreads();   // everyone done reading Ks before Ps overwrites it

    // mask + softmax (row = q, spread over 16 lanes x 12 frags)
    const int lq = w * 16 + (lane >> 4) * 4;
    float mx[4] = {-1e30f, -1e30f, -1e30f, -1e30f};
#pragma unroll
    for (int cf = 0; cf < 12; ++cf) {
        const int key = t0 + cf * 16 + (lane & 15);
#pragma unroll
        for (int r = 0; r < 4; ++r) {
            const int dd = (qs + lq + r) - key;
            const bool ok = (key < t1) && (dd <= 64) && (dd >= -64);
            const float sv = ok ? sa[cf][r] * 0.125f : -1e30f;
            sa[cf][r] = sv;
            mx[r] = fmaxf(mx[r], sv);
        }
    }
#pragma unroll
    for (int r = 0; r < 4; ++r)
#pragma unroll
        for (int o = 1; o < 16; o <<= 1)
            mx[r] = fmaxf(mx[r], __shfl_xor(mx[r], o));

    unsigned short* Ps = KP;   // [64][200]
    float sm[4] = {0.0f, 0.0f, 0.0f, 0.0f};
#pragma unroll
    for (int cf = 0; cf < 12; ++cf) {
#pragma unroll
        for (int r = 0; r < 4; ++r) {
            const float p = __expf(sa[cf][r] - mx[r]);   // masked -> 0
            sm[r] += p;
            Ps[(lq + r) * 200 + cf * 16 + (lane & 15)] = f2bf(p);
        }
    }
#pragma unroll
    for (int r = 0; r < 4; ++r)
#pragma unroll
        for (int o = 1; o < 16; o <<= 1)
            sm[r] += __shfl_xor(sm[r], o);

    // O = P V : per wave 16 q-rows x 64 dh, 4 col-frags, K=192 (6 ksteps)
    // (wave reads only its own Ps rows -> no barrier needed)
    f32x4 oa[4];
#pragma unroll
    for (int i = 0; i < 4; ++i) oa[i] = zero4;
#pragma unroll
    for (int ks = 0; ks < 6; ++ks) {
        const bf16x8 ap = *(const bf16x8*)&Ps[(w * 16 + (lane & 15)) * 200 + ks * 32 + (lane >> 4) * 8];
#pragma unroll
        for (int nf = 0; nf < 4; ++nf) {
            const bf16x8 bv = *(const bf16x8*)&Vts[nf * 16 + (lane & 15)][ks * 32 + (lane >> 4) * 8];
            oa[nf] = MFMA16(ap, bv, oa[nf]);
        }
    }
#pragma unroll
    for (int nf = 0; nf < 4; ++nf) {
#pragma unroll
        for (int r = 0; r < 4; ++r) {
            const float o = oa[nf][r] / sm[r];
            ctx[((size_t)(b * T_ + qs + lq + r)) * D_ + h * DH_ + nf * 16 + (lane & 15)] = f2bf(o);
        }
    }
}

// ---------------- orchestration ----------------
extern "C" void kernel_launch(void* const* d_in, const int* in_sizes, int n_in,
                              void* d_out, int out_size, void* d_ws, size_t ws_size,
                              hipStream_t stream)
{
    const float* x   = (const float*)d_in[0];
    const float* Wq  = (const float*)d_in[1];
    const float* bq  = (const float*)d_in[2];
    const float* Wk  = (const float*)d_in[3];
    const float* bk  = (const float*)d_in[4];
    const float* Wv  = (const float*)d_in[5];
    const float* bv  = (const float*)d_in[6];
    const float* Wo  = (const float*)d_in[7];
    const float* bo  = (const float*)d_in[8];
    const float* W1  = (const float*)d_in[9];
    const float* b1  = (const float*)d_in[10];
    const float* W2  = (const float*)d_in[11];
    const float* b2  = (const float*)d_in[12];
    const float* g1  = (const float*)d_in[13];
    const float* be1 = (const float*)d_in[14];
    const float* g2  = (const float*)d_in[15];
    const float* be2 = (const float*)d_in[16];
    float* out = (float*)d_out;

    // workspace layout (bytes): weights 14.2MB | hbuf 12.6 | qbuf 12.6 | x2 25.2 | ff 50.3
    unsigned short* wq_t = (unsigned short*)d_ws;          // [768][768]
    unsigned short* wk_t = wq_t + 589824;
    unsigned short* wv_t = wk_t + 589824;
    unsigned short* wo_t = wv_t + 589824;
    unsigned short* w1_t = wo_t + 589824;                  // [3072][768]
    unsigned short* w2_t = w1_t + 2359296;                 // [768][3072]
    unsigned short* hbuf = w2_t + 2359296;                 // h1, later ctx
    unsigned short* qbuf = hbuf + 6291456;                 // q, later h2
    float* x2 = (float*)(qbuf + 6291456);                  // fp32 [8192][768]
    unsigned short* kbuf = (unsigned short*)(x2 + 6291456);
    unsigned short* vtb  = kbuf + 6291456;                 // [4][768][2048]
    unsigned short* ffb  = kbuf;                           // [8192][3072] over k/vt/extra

    dim3 tb(32, 8);
    tcvt_kernel<<<dim3(24, 24), tb, 0, stream>>>(Wq, wq_t, 768, 768);
    tcvt_kernel<<<dim3(24, 24), tb, 0, stream>>>(Wk, wk_t, 768, 768);
    tcvt_kernel<<<dim3(24, 24), tb, 0, stream>>>(Wv, wv_t, 768, 768);
    tcvt_kernel<<<dim3(24, 24), tb, 0, stream>>>(Wo, wo_t, 768, 768);
    tcvt_kernel<<<dim3(96, 24), tb, 0, stream>>>(W1, w1_t, 768, 3072);
    tcvt_kernel<<<dim3(24, 96), tb, 0, stream>>>(W2, w2_t, 3072, 768);

    ln_kernel<<<8192, 256, 0, stream>>>(x, g1, be1, hbuf);

    gemm_bf16<0><<<dim3(64, 6), 256, 0, stream>>>(hbuf, wq_t, bq, nullptr, qbuf, 8192, 768, 768);
    gemm_bf16<0><<<dim3(64, 6), 256, 0, stream>>>(hbuf, wk_t, bk, nullptr, kbuf, 8192, 768, 768);
    gemm_bf16<1><<<dim3(64, 6), 256, 0, stream>>>(hbuf, wv_t, bv, nullptr, vtb, 8192, 768, 768);

    attn_kernel<<<1536, 256, 0, stream>>>(qbuf, kbuf, vtb, hbuf);   // ctx -> hbuf

    gemm_bf16<3><<<dim3(64, 6), 256, 0, stream>>>(hbuf, wo_t, bo, x, x2, 8192, 768, 768);

    ln_kernel<<<8192, 256, 0, stream>>>(x2, g2, be2, qbuf);         // h2 -> qbuf

    gemm_bf16<2><<<dim3(64, 24), 256, 0, stream>>>(qbuf, w1_t, b1, nullptr, ffb, 8192, 3072, 768);

    gemm_bf16<3><<<dim3(64, 6), 256, 0, stream>>>(ffb, w2_t, b2, x2, out, 8192, 768, 3072);
}

// Round 2
// 295.013 us; speedup vs baseline: 1.0393x; 1.0393x over previous
//
#include <hip/hip_runtime.h>
#include <hip/hip_bf16.h>

#define B_  4
#define T_  2048
#define D_  768
#define H_  12
#define DH_ 64
#define FF_ 3072

typedef __attribute__((ext_vector_type(8))) short bf16x8;
typedef __attribute__((ext_vector_type(4))) float f32x4;
typedef __attribute__((ext_vector_type(4))) unsigned short us4;

#define MFMA16(a, b, c) __builtin_amdgcn_mfma_f32_16x16x32_bf16((a), (b), (c), 0, 0, 0)

__device__ __forceinline__ unsigned short f2bf(float f) {
    union { float f; unsigned u; } v; v.f = f;
    unsigned r = v.u + 0x7fffu + ((v.u >> 16) & 1u);
    return (unsigned short)(r >> 16);
}

// async global->LDS, 16B per lane. LDS dest must be wave-uniform; HW adds lane*16.
__device__ __forceinline__ void gload_lds16(const unsigned short* gp, unsigned short* lp) {
    __builtin_amdgcn_global_load_lds(
        (const __attribute__((address_space(1))) unsigned int*)gp,
        (__attribute__((address_space(3))) unsigned int*)lp,
        16, 0, 0);
}

// ---------------- weight convert + transpose: src[K][N] f32 -> dst[N][K] bf16 ----------
__global__ __launch_bounds__(256) void tcvt_kernel(
    const float* __restrict__ src, unsigned short* __restrict__ dst, int K, int N)
{
    __shared__ float tile[32][33];
    const int bx = blockIdx.x * 32;  // N dim
    const int by = blockIdx.y * 32;  // K dim
    const int tx = threadIdx.x, ty = threadIdx.y;  // 32 x 8
#pragma unroll
    for (int i = 0; i < 32; i += 8)
        tile[ty + i][tx] = src[(size_t)(by + ty + i) * N + bx + tx];
    __syncthreads();
#pragma unroll
    for (int i = 0; i < 32; i += 8)
        dst[(size_t)(bx + ty + i) * K + by + tx] = f2bf(tile[tx][ty + i]);
}

// batched version for the four 768x768 weights (Wq,Wk,Wv,Wo -> contiguous dst)
__global__ __launch_bounds__(256) void tcvt4_kernel(
    const float* __restrict__ s0, const float* __restrict__ s1,
    const float* __restrict__ s2, const float* __restrict__ s3,
    unsigned short* __restrict__ dst)
{
    __shared__ float tile[32][33];
    const int z = blockIdx.z;
    const float* src = (z == 0) ? s0 : (z == 1) ? s1 : (z == 2) ? s2 : s3;
    unsigned short* d = dst + (size_t)z * 589824;
    const int bx = blockIdx.x * 32;
    const int by = blockIdx.y * 32;
    const int tx = threadIdx.x, ty = threadIdx.y;
#pragma unroll
    for (int i = 0; i < 32; i += 8)
        tile[ty + i][tx] = src[(size_t)(by + ty + i) * 768 + bx + tx];
    __syncthreads();
#pragma unroll
    for (int i = 0; i < 32; i += 8)
        d[(size_t)(bx + ty + i) * 768 + by + tx] = f2bf(tile[tx][ty + i]);
}

// ---------------- LayerNorm: fp32 in -> bf16 out ----------------
__global__ __launch_bounds__(256) void ln_kernel(
    const float* __restrict__ x, const float* __restrict__ g,
    const float* __restrict__ be, unsigned short* __restrict__ out)
{
    const int row = blockIdx.x;
    const int t = threadIdx.x;
    const float* xr = x + (size_t)row * D_;
    float v0 = xr[t], v1 = xr[t + 256], v2 = xr[t + 512];
    float s = v0 + v1 + v2;
    float s2 = v0 * v0 + v1 * v1 + v2 * v2;
#pragma unroll
    for (int o = 1; o < 64; o <<= 1) {
        s  += __shfl_xor(s,  o);
        s2 += __shfl_xor(s2, o);
    }
    __shared__ float rs[4], rq[4];
    const int wave = t >> 6;
    if ((t & 63) == 0) { rs[wave] = s; rq[wave] = s2; }
    __syncthreads();
    s  = rs[0] + rs[1] + rs[2] + rs[3];
    s2 = rq[0] + rq[1] + rq[2] + rq[3];
    const float mu = s * (1.0f / D_);
    const float var = s2 * (1.0f / D_) - mu * mu;
    const float rstd = rsqrtf(var + 1e-5f);
    unsigned short* orow = out + (size_t)row * D_;
    orow[t]       = f2bf((v0 - mu) * rstd * g[t]       + be[t]);
    orow[t + 256] = f2bf((v1 - mu) * rstd * g[t + 256] + be[t + 256]);
    orow[t + 512] = f2bf((v2 - mu) * rstd * g[t + 512] + be[t + 512]);
}

// ---------------- GEMM: C[M][N] = A[M][K] * Bt[N][K]^T + bias ----------------
// BM=128, BK=32, BN in {128, 64}; 256 threads (4 waves).
// BN=128: waves 2x2, wave tile 64x64 (acc 4x4). BN=64: waves 4x1, wave tile 32x64 (acc 2x4).
// MODE 0: bf16 out [M][N]
// MODE 2: gelu(exact) -> bf16 out [M][N]
// MODE 3: fp32 out [M][N] = acc + bias + resid
// MODE 4: fused QKV routing: gn<768 -> Q bf16 [M][768]; <1536 -> K bf16 [M][768];
//         else -> V bf16 transposed out3[b][gn-1536][t]
template<int MODE, int BN>
__global__ __launch_bounds__(256) void gemm_bf16(
    const unsigned short* __restrict__ A,
    const unsigned short* __restrict__ Bt,
    const float* __restrict__ bias,
    const float* __restrict__ bias2,
    const float* __restrict__ bias3,
    const float* __restrict__ resid,
    void* __restrict__ outp,
    void* __restrict__ out2,
    void* __restrict__ out3,
    int M, int N, int K)
{
    constexpr int MM = (BN == 128) ? 4 : 2;
    __shared__ __align__(16) unsigned short As[128 * 32];
    __shared__ __align__(16) unsigned short Bs[BN * 32];
    const int tid = threadIdx.x;
    const int wave = tid >> 6;
    const int lane = tid & 63;
    const int n0 = blockIdx.x * BN;
    const int m0 = blockIdx.y * 128;
    const int wr = (BN == 128) ? (wave >> 1) : wave;
    const int wc = (BN == 128) ? (wave & 1) : 0;

    f32x4 zero4 = {0.0f, 0.0f, 0.0f, 0.0f};
    f32x4 acc[MM][4];
#pragma unroll
    for (int i = 0; i < MM; ++i)
#pragma unroll
        for (int j = 0; j < 4; ++j) acc[i][j] = zero4;

    // staging: 1KB chunks (16 rows x 32 cols bf16); A has 8 chunks, B has BN/16.
    const int srow = lane >> 2;          // 0..15
    const int scol = (lane & 3) * 8;     // 0,8,16,24
    const int ach0 = wave * 2;
    const size_t a_base0 = (size_t)(m0 + ach0 * 16 + srow) * K + scol;
    const size_t a_base1 = a_base0 + (size_t)16 * K;
    unsigned short* As0 = As + ach0 * 512;
    const int bch0 = (BN == 128) ? wave * 2 : wave;
    const size_t b_base0 = (size_t)(n0 + bch0 * 16 + srow) * K + scol;
    const size_t b_base1 = b_base0 + (size_t)16 * K;   // only used BN=128
    unsigned short* Bs0 = Bs + bch0 * 512;

    const int nk = K >> 5;
    for (int kt = 0; kt < nk; ++kt) {
        const int k0 = kt << 5;
        __syncthreads();
        gload_lds16(A  + a_base0 + k0, As0);
        gload_lds16(A  + a_base1 + k0, As0 + 512);
        gload_lds16(Bt + b_base0 + k0, Bs0);
        if (BN == 128) gload_lds16(Bt + b_base1 + k0, Bs0 + 512);
        __syncthreads();
        bf16x8 afr[MM], bfr[4];
#pragma unroll
        for (int mm = 0; mm < MM; ++mm)
            afr[mm] = *(const bf16x8*)(As + (wr * (MM * 16) + mm * 16 + (lane & 15)) * 32 + (lane >> 4) * 8);
#pragma unroll
        for (int nn = 0; nn < 4; ++nn)
            bfr[nn] = *(const bf16x8*)(Bs + (wc * 64 + nn * 16 + (lane & 15)) * 32 + (lane >> 4) * 8);
#pragma unroll
        for (int mm = 0; mm < MM; ++mm)
#pragma unroll
            for (int nn = 0; nn < 4; ++nn)
                acc[mm][nn] = MFMA16(afr[mm], bfr[nn], acc[mm][nn]);
    }

    const int lc = lane & 15;
    const int lr = (lane >> 4) * 4;
#pragma unroll
    for (int mm = 0; mm < MM; ++mm) {
        const int gm0 = m0 + wr * (MM * 16) + mm * 16 + lr;
#pragma unroll
        for (int nn = 0; nn < 4; ++nn) {
            const int gn = n0 + wc * 64 + nn * 16 + lc;
            if (MODE == 4) {
                if (gn < 1536) {
                    const float bv = (gn < 768) ? bias[gn] : bias2[gn - 768];
                    unsigned short* o = (gn < 768) ? (unsigned short*)outp : (unsigned short*)out2;
                    const int col = (gn < 768) ? gn : gn - 768;
#pragma unroll
                    for (int r = 0; r < 4; ++r)
                        o[(size_t)(gm0 + r) * 768 + col] = f2bf(acc[mm][nn][r] + bv);
                } else {
                    const float bv = bias3[gn - 1536];
                    const int b = gm0 / T_;
                    const int tl = gm0 - b * T_;
                    us4 pk;
#pragma unroll
                    for (int r = 0; r < 4; ++r) pk[r] = f2bf(acc[mm][nn][r] + bv);
                    *(us4*)((unsigned short*)out3 + ((size_t)(b * D_ + gn - 1536)) * T_ + tl) = pk;
                }
            } else {
                const float bv = bias[gn];
#pragma unroll
                for (int r = 0; r < 4; ++r) {
                    const int gm = gm0 + r;
                    float v = acc[mm][nn][r] + bv;
                    if (MODE == 0) {
                        ((unsigned short*)outp)[(size_t)gm * N + gn] = f2bf(v);
                    } else if (MODE == 2) {
                        v = 0.5f * v * (1.0f + erff(v * 0.70710678118654752f));
                        ((unsigned short*)outp)[(size_t)gm * N + gn] = f2bf(v);
                    } else if (MODE == 3) {
                        ((float*)outp)[(size_t)gm * N + gn] = v + resid[(size_t)gm * N + gn];
                    }
                }
            }
        }
    }
}

// ---------------- banded flash attention ----------------
// block = 256 threads (4 waves), handles (b, h, 64-query tile)
// K/V window = [t0, t1), KW <= 192
__global__ __launch_bounds__(256) void attn_kernel(
    const unsigned short* __restrict__ Q,    // [B*T][768]
    const unsigned short* __restrict__ Kg,   // [B*T][768]
    const unsigned short* __restrict__ Vt,   // [B][768][T]
    unsigned short* __restrict__ ctx)        // [B*T][768]
{
    __shared__ __align__(16) unsigned short Qs[64][72];
    __shared__ __align__(16) unsigned short KP[192 * 72];   // Ks[192][72], later Ps[64][200]
    __shared__ __align__(16) unsigned short Vts[64][200];

    const int tid = threadIdx.x;
    const int lane = tid & 63;
    const int w = tid >> 6;
    const int bid = blockIdx.x;
    const int qt = bid & 31;
    const int h = (bid >> 5) % H_;
    const int b = bid / (32 * H_);
    const int qs = qt * 64;
    const int t0 = qs >= 64 ? qs - 64 : 0;
    const int t1 = (qs + 128 < T_) ? qs + 128 : T_;
    const int KW = t1 - t0;

    // stage Q (64 rows x 64 cols)
    for (int s = tid; s < 512; s += 256) {
        const int r = s >> 3, c8 = (s & 7) << 3;
        *(uint4*)&Qs[r][c8] =
            *(const uint4*)&Q[((size_t)(b * T_ + qs + r)) * D_ + h * DH_ + c8];
    }
    // stage K (192 rows x 64), zero-filled beyond window
    unsigned short* Ks = KP;
    for (int s = tid; s < 1536; s += 256) {
        const int r = s >> 3, c8 = (s & 7) << 3;
        uint4 val = {0, 0, 0, 0};
        if (r < KW)
            val = *(const uint4*)&Kg[((size_t)(b * T_ + t0 + r)) * D_ + h * DH_ + c8];
        *(uint4*)&Ks[r * 72 + c8] = val;
    }
    // stage V^T (64 dh-rows x 192 key-cols), zero-filled beyond window
    for (int s = tid; s < 1536; s += 256) {
        const int r = s / 24, c8 = (s % 24) << 3;
        uint4 val = {0, 0, 0, 0};
        if (c8 < KW)
            val = *(const uint4*)&Vt[((size_t)((b * H_ + h) * DH_ + r)) * T_ + t0 + c8];
        *(uint4*)&Vts[r][c8] = val;
    }
    __syncthreads();

    // S = Q K^T : per wave 16 q-rows x 192 keys, 12 col-frags, K=64 (2 ksteps)
    f32x4 zero4 = {0.0f, 0.0f, 0.0f, 0.0f};
    f32x4 sa[12];
#pragma unroll
    for (int i = 0; i < 12; ++i) sa[i] = zero4;
#pragma unroll
    for (int ks = 0; ks < 2; ++ks) {
        const bf16x8 aq = *(const bf16x8*)&Qs[w * 16 + (lane & 15)][ks * 32 + (lane >> 4) * 8];
#pragma unroll
        for (int cf = 0; cf < 12; ++cf) {
            const bf16x8 bk = *(const bf16x8*)&Ks[(cf * 16 + (lane & 15)) * 72 + ks * 32 + (lane >> 4) * 8];
            sa[cf] = MFMA16(aq, bk, sa[cf]);
        }
    }
    __syncthreads();   // everyone done reading Ks before Ps overwrites it

    // mask + softmax (row = q, spread over 16 lanes x 12 frags)
    const int lq = w * 16 + (lane >> 4) * 4;
    float mx[4] = {-1e30f, -1e30f, -1e30f, -1e30f};
#pragma unroll
    for (int cf = 0; cf < 12; ++cf) {
        const int key = t0 + cf * 16 + (lane & 15);
#pragma unroll
        for (int r = 0; r < 4; ++r) {
            const int dd = (qs + lq + r) - key;
            const bool ok = (key < t1) && (dd <= 64) && (dd >= -64);
            const float sv = ok ? sa[cf][r] * 0.125f : -1e30f;
            sa[cf][r] = sv;
            mx[r] = fmaxf(mx[r], sv);
        }
    }
#pragma unroll
    for (int r = 0; r < 4; ++r)
#pragma unroll
        for (int o = 1; o < 16; o <<= 1)
            mx[r] = fmaxf(mx[r], __shfl_xor(mx[r], o));

    unsigned short* Ps = KP;   // [64][200]
    float sm[4] = {0.0f, 0.0f, 0.0f, 0.0f};
#pragma unroll
    for (int cf = 0; cf < 12; ++cf) {
#pragma unroll
        for (int r = 0; r < 4; ++r) {
            const float p = __expf(sa[cf][r] - mx[r]);   // masked -> 0
            sm[r] += p;
            Ps[(lq + r) * 200 + cf * 16 + (lane & 15)] = f2bf(p);
        }
    }
#pragma unroll
    for (int r = 0; r < 4; ++r)
#pragma unroll
        for (int o = 1; o < 16; o <<= 1)
            sm[r] += __shfl_xor(sm[r], o);

    // O = P V : per wave 16 q-rows x 64 dh, 4 col-frags, K=192 (6 ksteps)
    f32x4 oa[4];
#pragma unroll
    for (int i = 0; i < 4; ++i) oa[i] = zero4;
#pragma unroll
    for (int ks = 0; ks < 6; ++ks) {
        const bf16x8 ap = *(const bf16x8*)&Ps[(w * 16 + (lane & 15)) * 200 + ks * 32 + (lane >> 4) * 8];
#pragma unroll
        for (int nf = 0; nf < 4; ++nf) {
            const bf16x8 bv = *(const bf16x8*)&Vts[nf * 16 + (lane & 15)][ks * 32 + (lane >> 4) * 8];
            oa[nf] = MFMA16(ap, bv, oa[nf]);
        }
    }
#pragma unroll
    for (int nf = 0; nf < 4; ++nf) {
#pragma unroll
        for (int r = 0; r < 4; ++r) {
            const float o = oa[nf][r] / sm[r];
            ctx[((size_t)(b * T_ + qs + lq + r)) * D_ + h * DH_ + nf * 16 + (lane & 15)] = f2bf(o);
        }
    }
}

// ---------------- orchestration ----------------
extern "C" void kernel_launch(void* const* d_in, const int* in_sizes, int n_in,
                              void* d_out, int out_size, void* d_ws, size_t ws_size,
                              hipStream_t stream)
{
    const float* x   = (const float*)d_in[0];
    const float* Wq  = (const float*)d_in[1];
    const float* bq  = (const float*)d_in[2];
    const float* Wk  = (const float*)d_in[3];
    const float* bk  = (const float*)d_in[4];
    const float* Wv  = (const float*)d_in[5];
    const float* bv  = (const float*)d_in[6];
    const float* Wo  = (const float*)d_in[7];
    const float* bo  = (const float*)d_in[8];
    const float* W1  = (const float*)d_in[9];
    const float* b1  = (const float*)d_in[10];
    const float* W2  = (const float*)d_in[11];
    const float* b2  = (const float*)d_in[12];
    const float* g1  = (const float*)d_in[13];
    const float* be1 = (const float*)d_in[14];
    const float* g2  = (const float*)d_in[15];
    const float* be2 = (const float*)d_in[16];
    float* out = (float*)d_out;

    // workspace layout (elements/bytes):
    // wqkv_t [2304][768] bf16 (wq/wk/wv contiguous), wo_t, w1_t, w2_t | hbuf | qbuf | x2 f32 | kbuf | vtb | ffb over kbuf..
    unsigned short* wqkv_t = (unsigned short*)d_ws;        // 3 x [768][768]
    unsigned short* wo_t = wqkv_t + 3 * 589824;
    unsigned short* w1_t = wo_t + 589824;                  // [3072][768]
    unsigned short* w2_t = w1_t + 2359296;                 // [768][3072]
    unsigned short* hbuf = w2_t + 2359296;                 // h1, later ctx
    unsigned short* qbuf = hbuf + 6291456;                 // q, later h2
    float* x2 = (float*)(qbuf + 6291456);                  // fp32 [8192][768]
    unsigned short* kbuf = (unsigned short*)(x2 + 6291456);
    unsigned short* vtb  = kbuf + 6291456;                 // [4][768][2048]
    unsigned short* ffb  = kbuf;                           // [8192][3072] over k/vt/extra

    dim3 tb(32, 8);
    tcvt4_kernel<<<dim3(24, 24, 4), tb, 0, stream>>>(Wq, Wk, Wv, Wo, wqkv_t);
    tcvt_kernel<<<dim3(96, 24), tb, 0, stream>>>(W1, w1_t, 768, 3072);
    tcvt_kernel<<<dim3(24, 96), tb, 0, stream>>>(W2, w2_t, 3072, 768);

    ln_kernel<<<8192, 256, 0, stream>>>(x, g1, be1, hbuf);

    // fused QKV: N = 2304, routes Q->qbuf, K->kbuf, V->vtb(transposed)
    gemm_bf16<4, 128><<<dim3(18, 64), 256, 0, stream>>>(
        hbuf, wqkv_t, bq, bk, bv, nullptr, qbuf, kbuf, vtb, 8192, 2304, 768);

    attn_kernel<<<1536, 256, 0, stream>>>(qbuf, kbuf, vtb, hbuf);   // ctx -> hbuf

    gemm_bf16<3, 64><<<dim3(12, 64), 256, 0, stream>>>(
        hbuf, wo_t, bo, nullptr, nullptr, x, x2, nullptr, nullptr, 8192, 768, 768);

    ln_kernel<<<8192, 256, 0, stream>>>(x2, g2, be2, qbuf);         // h2 -> qbuf

    gemm_bf16<2, 128><<<dim3(24, 64), 256, 0, stream>>>(
        qbuf, w1_t, b1, nullptr, nullptr, nullptr, ffb, nullptr, nullptr, 8192, 3072, 768);

    gemm_bf16<3, 64><<<dim3(12, 64), 256, 0, stream>>>(
        ffb, w2_t, b2, nullptr, nullptr, x2, out, nullptr, nullptr, 8192, 768, 3072);
}

// Round 3
// 232.944 us; speedup vs baseline: 1.3162x; 1.2665x over previous
//
#include <hip/hip_runtime.h>
#include <hip/hip_bf16.h>

#define B_  4
#define T_  2048
#define D_  768
#define H_  12
#define DH_ 64
#define FF_ 3072

typedef __attribute__((ext_vector_type(8))) short bf16x8;
typedef __attribute__((ext_vector_type(4))) float f32x4;
typedef __attribute__((ext_vector_type(4))) unsigned short us4;

#define MFMA16(a, b, c) __builtin_amdgcn_mfma_f32_16x16x32_bf16((a), (b), (c), 0, 0, 0)

__device__ __forceinline__ unsigned short f2bf(float f) {
    union { float f; unsigned u; } v; v.f = f;
    unsigned r = v.u + 0x7fffu + ((v.u >> 16) & 1u);
    return (unsigned short)(r >> 16);
}

// async global->LDS, 16B per lane. LDS dest must be wave-uniform; HW adds lane*16.
__device__ __forceinline__ void gload_lds16(const unsigned short* gp, unsigned short* lp) {
    __builtin_amdgcn_global_load_lds(
        (const __attribute__((address_space(1))) unsigned int*)gp,
        (__attribute__((address_space(3))) unsigned int*)lp,
        16, 0, 0);
}

// ---------------- weight convert + transpose: src[K][N] f32 -> dst[N][K] bf16 ----------
__global__ __launch_bounds__(256) void tcvt_kernel(
    const float* __restrict__ src, unsigned short* __restrict__ dst, int K, int N)
{
    __shared__ float tile[32][33];
    const int bx = blockIdx.x * 32;  // N dim
    const int by = blockIdx.y * 32;  // K dim
    const int tx = threadIdx.x, ty = threadIdx.y;  // 32 x 8
#pragma unroll
    for (int i = 0; i < 32; i += 8)
        tile[ty + i][tx] = src[(size_t)(by + ty + i) * N + bx + tx];
    __syncthreads();
#pragma unroll
    for (int i = 0; i < 32; i += 8)
        dst[(size_t)(bx + ty + i) * K + by + tx] = f2bf(tile[tx][ty + i]);
}

// batched version for the four 768x768 weights (Wq,Wk,Wv,Wo -> contiguous dst)
__global__ __launch_bounds__(256) void tcvt4_kernel(
    const float* __restrict__ s0, const float* __restrict__ s1,
    const float* __restrict__ s2, const float* __restrict__ s3,
    unsigned short* __restrict__ dst)
{
    __shared__ float tile[32][33];
    const int z = blockIdx.z;
    const float* src = (z == 0) ? s0 : (z == 1) ? s1 : (z == 2) ? s2 : s3;
    unsigned short* d = dst + (size_t)z * 589824;
    const int bx = blockIdx.x * 32;
    const int by = blockIdx.y * 32;
    const int tx = threadIdx.x, ty = threadIdx.y;
#pragma unroll
    for (int i = 0; i < 32; i += 8)
        tile[ty + i][tx] = src[(size_t)(by + ty + i) * 768 + bx + tx];
    __syncthreads();
#pragma unroll
    for (int i = 0; i < 32; i += 8)
        d[(size_t)(bx + ty + i) * 768 + by + tx] = f2bf(tile[tx][ty + i]);
}

// ---------------- LayerNorm: fp32 in -> bf16 out ----------------
__global__ __launch_bounds__(256) void ln_kernel(
    const float* __restrict__ x, const float* __restrict__ g,
    const float* __restrict__ be, unsigned short* __restrict__ out)
{
    const int row = blockIdx.x;
    const int t = threadIdx.x;
    const float* xr = x + (size_t)row * D_;
    float v0 = xr[t], v1 = xr[t + 256], v2 = xr[t + 512];
    float s = v0 + v1 + v2;
    float s2 = v0 * v0 + v1 * v1 + v2 * v2;
#pragma unroll
    for (int o = 1; o < 64; o <<= 1) {
        s  += __shfl_xor(s,  o);
        s2 += __shfl_xor(s2, o);
    }
    __shared__ float rs[4], rq[4];
    const int wave = t >> 6;
    if ((t & 63) == 0) { rs[wave] = s; rq[wave] = s2; }
    __syncthreads();
    s  = rs[0] + rs[1] + rs[2] + rs[3];
    s2 = rq[0] + rq[1] + rq[2] + rq[3];
    const float mu = s * (1.0f / D_);
    const float var = s2 * (1.0f / D_) - mu * mu;
    const float rstd = rsqrtf(var + 1e-5f);
    unsigned short* orow = out + (size_t)row * D_;
    orow[t]       = f2bf((v0 - mu) * rstd * g[t]       + be[t]);
    orow[t + 256] = f2bf((v1 - mu) * rstd * g[t + 256] + be[t + 256]);
    orow[t + 512] = f2bf((v2 - mu) * rstd * g[t + 512] + be[t + 512]);
}

// ---------------- GEMM: C[M][N] = A[M][K] * Bt[N][K]^T + bias ----------------
// BM=128, BN=128, BK=64; 512 threads (8 waves as 4x2), wave-tile 32x64 (acc 2x4).
// LDS tiles XOR-swizzled at 16B granularity: global col-block cb of row r lives at
// LDS block cb^(r&7) (achieved by pre-swizzling the global SOURCE address; the
// global_load_lds destination stays linear). ds_read applies the same XOR.
// 1D grid, N-fastest, bijective XCD swizzle so same-A-panel blocks share an XCD L2.
// MODE 0: bf16 out [M][N]
// MODE 2: gelu(exact) -> bf16 out [M][N]
// MODE 3: fp32 out [M][N] = acc + bias + resid
// MODE 4: fused QKV routing: gn<768 -> Q bf16; <1536 -> K bf16; else V bf16
//         transposed out3[b][gn-1536][t]
template<int MODE>
__global__ __launch_bounds__(512) void gemm512(
    const unsigned short* __restrict__ A,
    const unsigned short* __restrict__ Bt,
    const float* __restrict__ bias,
    const float* __restrict__ bias2,
    const float* __restrict__ bias3,
    const float* __restrict__ resid,
    void* __restrict__ outp,
    void* __restrict__ out2,
    void* __restrict__ out3,
    int N, int K, int nTilesN)
{
    __shared__ __align__(16) unsigned short As[128 * 64];
    __shared__ __align__(16) unsigned short Bs[128 * 64];

    // bijective XCD swizzle (m204): consecutive swizzled ids land on one XCD
    const int nwg = gridDim.x;
    const int q = nwg >> 3, rr = nwg & 7;
    const int xcd = blockIdx.x & 7, loc = blockIdx.x >> 3;
    const int swz = (xcd < rr ? xcd * (q + 1) : rr * (q + 1) + (xcd - rr) * q) + loc;
    const int m0 = (swz / nTilesN) * 128;
    const int n0 = (swz % nTilesN) * 128;

    const int tid = threadIdx.x;
    const int wv = tid >> 6;
    const int lane = tid & 63;
    const int wr = wv >> 1;          // 0..3
    const int wc = wv & 1;           // 0..1

    f32x4 zero4 = {0.0f, 0.0f, 0.0f, 0.0f};
    f32x4 acc[2][4];
#pragma unroll
    for (int i = 0; i < 2; ++i)
#pragma unroll
        for (int j = 0; j < 4; ++j) acc[i][j] = zero4;

    // staging: each wave stages 16 rows (2 issues x 8 rows) of A and of B.
    // lane -> (row=lane>>3, blk=lane&7); source col-block = blk ^ (row&7)
    const int lrow = lane >> 3;
    const int scb = (lane & 7) ^ lrow;
    const size_t ag0 = (size_t)(m0 + wv * 16 + lrow) * K + scb * 8;
    const size_t ag1 = ag0 + (size_t)8 * K;
    const size_t bg0 = (size_t)(n0 + wv * 16 + lrow) * K + scb * 8;
    const size_t bg1 = bg0 + (size_t)8 * K;
    unsigned short* AsW = As + wv * 1024;
    unsigned short* BsW = Bs + wv * 1024;

    const int fr = lane & 15;        // fragment row within 16
    const int fg = lane >> 4;        // 0..3 col-block group
    const int sw = fr & 7;           // XOR key for ds_read

    const int nk = K >> 6;
    for (int kt = 0; kt < nk; ++kt) {
        const int k0 = kt << 6;
        __syncthreads();
        gload_lds16(A  + ag0 + k0, AsW);
        gload_lds16(A  + ag1 + k0, AsW + 512);
        gload_lds16(Bt + bg0 + k0, BsW);
        gload_lds16(Bt + bg1 + k0, BsW + 512);
        __syncthreads();
#pragma unroll
        for (int kk = 0; kk < 2; ++kk) {
            bf16x8 afr[2], bfr[4];
#pragma unroll
            for (int mm = 0; mm < 2; ++mm) {
                const int row = wr * 32 + mm * 16 + fr;
                afr[mm] = *(const bf16x8*)(As + row * 64 + (((kk * 4 + fg) ^ sw) << 3));
            }
#pragma unroll
            for (int nn = 0; nn < 4; ++nn) {
                const int row = wc * 64 + nn * 16 + fr;
                bfr[nn] = *(const bf16x8*)(Bs + row * 64 + (((kk * 4 + fg) ^ sw) << 3));
            }
#pragma unroll
            for (int mm = 0; mm < 2; ++mm)
#pragma unroll
                for (int nn = 0; nn < 4; ++nn)
                    acc[mm][nn] = MFMA16(afr[mm], bfr[nn], acc[mm][nn]);
        }
    }

    const int lc = lane & 15;
    const int lr = (lane >> 4) * 4;
#pragma unroll
    for (int mm = 0; mm < 2; ++mm) {
        const int gm0 = m0 + wr * 32 + mm * 16 + lr;
#pragma unroll
        for (int nn = 0; nn < 4; ++nn) {
            const int gn = n0 + wc * 64 + nn * 16 + lc;
            if (MODE == 4) {
                if (gn < 1536) {
                    const float bv = (gn < 768) ? bias[gn] : bias2[gn - 768];
                    unsigned short* o = (gn < 768) ? (unsigned short*)outp : (unsigned short*)out2;
                    const int col = (gn < 768) ? gn : gn - 768;
#pragma unroll
                    for (int r = 0; r < 4; ++r)
                        o[(size_t)(gm0 + r) * 768 + col] = f2bf(acc[mm][nn][r] + bv);
                } else {
                    const float bv = bias3[gn - 1536];
                    const int b = gm0 / T_;
                    const int tl = gm0 - b * T_;
                    us4 pk;
#pragma unroll
                    for (int r = 0; r < 4; ++r) pk[r] = f2bf(acc[mm][nn][r] + bv);
                    *(us4*)((unsigned short*)out3 + ((size_t)(b * D_ + gn - 1536)) * T_ + tl) = pk;
                }
            } else {
                const float bv = bias[gn];
#pragma unroll
                for (int r = 0; r < 4; ++r) {
                    const int gm = gm0 + r;
                    float v = acc[mm][nn][r] + bv;
                    if (MODE == 0) {
                        ((unsigned short*)outp)[(size_t)gm * N + gn] = f2bf(v);
                    } else if (MODE == 2) {
                        v = 0.5f * v * (1.0f + erff(v * 0.70710678118654752f));
                        ((unsigned short*)outp)[(size_t)gm * N + gn] = f2bf(v);
                    } else if (MODE == 3) {
                        ((float*)outp)[(size_t)gm * N + gn] = v + resid[(size_t)gm * N + gn];
                    }
                }
            }
        }
    }
}

// ---------------- banded flash attention ----------------
// block = 256 threads (4 waves), handles (b, h, 64-query tile)
// K/V window = [t0, t1), KW <= 192
__global__ __launch_bounds__(256) void attn_kernel(
    const unsigned short* __restrict__ Q,    // [B*T][768]
    const unsigned short* __restrict__ Kg,   // [B*T][768]
    const unsigned short* __restrict__ Vt,   // [B][768][T]
    unsigned short* __restrict__ ctx)        // [B*T][768]
{
    __shared__ __align__(16) unsigned short Qs[64][72];
    __shared__ __align__(16) unsigned short KP[192 * 72];   // Ks[192][72], later Ps[64][200]
    __shared__ __align__(16) unsigned short Vts[64][200];

    const int tid = threadIdx.x;
    const int lane = tid & 63;
    const int w = tid >> 6;
    const int bid = blockIdx.x;
    const int qt = bid & 31;
    const int h = (bid >> 5) % H_;
    const int b = bid / (32 * H_);
    const int qs = qt * 64;
    const int t0 = qs >= 64 ? qs - 64 : 0;
    const int t1 = (qs + 128 < T_) ? qs + 128 : T_;
    const int KW = t1 - t0;

    // stage Q (64 rows x 64 cols)
    for (int s = tid; s < 512; s += 256) {
        const int r = s >> 3, c8 = (s & 7) << 3;
        *(uint4*)&Qs[r][c8] =
            *(const uint4*)&Q[((size_t)(b * T_ + qs + r)) * D_ + h * DH_ + c8];
    }
    // stage K (192 rows x 64), zero-filled beyond window
    unsigned short* Ks = KP;
    for (int s = tid; s < 1536; s += 256) {
        const int r = s >> 3, c8 = (s & 7) << 3;
        uint4 val = {0, 0, 0, 0};
        if (r < KW)
            val = *(const uint4*)&Kg[((size_t)(b * T_ + t0 + r)) * D_ + h * DH_ + c8];
        *(uint4*)&Ks[r * 72 + c8] = val;
    }
    // stage V^T (64 dh-rows x 192 key-cols), zero-filled beyond window
    for (int s = tid; s < 1536; s += 256) {
        const int r = s / 24, c8 = (s % 24) << 3;
        uint4 val = {0, 0, 0, 0};
        if (c8 < KW)
            val = *(const uint4*)&Vt[((size_t)((b * H_ + h) * DH_ + r)) * T_ + t0 + c8];
        *(uint4*)&Vts[r][c8] = val;
    }
    __syncthreads();

    // S = Q K^T : per wave 16 q-rows x 192 keys, 12 col-frags, K=64 (2 ksteps)
    f32x4 zero4 = {0.0f, 0.0f, 0.0f, 0.0f};
    f32x4 sa[12];
#pragma unroll
    for (int i = 0; i < 12; ++i) sa[i] = zero4;
#pragma unroll
    for (int ks = 0; ks < 2; ++ks) {
        const bf16x8 aq = *(const bf16x8*)&Qs[w * 16 + (lane & 15)][ks * 32 + (lane >> 4) * 8];
#pragma unroll
        for (int cf = 0; cf < 12; ++cf) {
            const bf16x8 bk = *(const bf16x8*)&Ks[(cf * 16 + (lane & 15)) * 72 + ks * 32 + (lane >> 4) * 8];
            sa[cf] = MFMA16(aq, bk, sa[cf]);
        }
    }
    __syncthreads();   // everyone done reading Ks before Ps overwrites it

    // mask + softmax (row = q, spread over 16 lanes x 12 frags)
    const int lq = w * 16 + (lane >> 4) * 4;
    float mx[4] = {-1e30f, -1e30f, -1e30f, -1e30f};
#pragma unroll
    for (int cf = 0; cf < 12; ++cf) {
        const int key = t0 + cf * 16 + (lane & 15);
#pragma unroll
        for (int r = 0; r < 4; ++r) {
            const int dd = (qs + lq + r) - key;
            const bool ok = (key < t1) && (dd <= 64) && (dd >= -64);
            const float sv = ok ? sa[cf][r] * 0.125f : -1e30f;
            sa[cf][r] = sv;
            mx[r] = fmaxf(mx[r], sv);
        }
    }
#pragma unroll
    for (int r = 0; r < 4; ++r)
#pragma unroll
        for (int o = 1; o < 16; o <<= 1)
            mx[r] = fmaxf(mx[r], __shfl_xor(mx[r], o));

    unsigned short* Ps = KP;   // [64][200]
    float sm[4] = {0.0f, 0.0f, 0.0f, 0.0f};
#pragma unroll
    for (int cf = 0; cf < 12; ++cf) {
#pragma unroll
        for (int r = 0; r < 4; ++r) {
            const float p = __expf(sa[cf][r] - mx[r]);   // masked -> 0
            sm[r] += p;
            Ps[(lq + r) * 200 + cf * 16 + (lane & 15)] = f2bf(p);
        }
    }
#pragma unroll
    for (int r = 0; r < 4; ++r)
#pragma unroll
        for (int o = 1; o < 16; o <<= 1)
            sm[r] += __shfl_xor(sm[r], o);

    // O = P V : per wave 16 q-rows x 64 dh, 4 col-frags, K=192 (6 ksteps)
    f32x4 oa[4];
#pragma unroll
    for (int i = 0; i < 4; ++i) oa[i] = zero4;
#pragma unroll
    for (int ks = 0; ks < 6; ++ks) {
        const bf16x8 ap = *(const bf16x8*)&Ps[(w * 16 + (lane & 15)) * 200 + ks * 32 + (lane >> 4) * 8];
#pragma unroll
        for (int nf = 0; nf < 4; ++nf) {
            const bf16x8 bv = *(const bf16x8*)&Vts[nf * 16 + (lane & 15)][ks * 32 + (lane >> 4) * 8];
            oa[nf] = MFMA16(ap, bv, oa[nf]);
        }
    }
#pragma unroll
    for (int nf = 0; nf < 4; ++nf) {
#pragma unroll
        for (int r = 0; r < 4; ++r) {
            const float o = oa[nf][r] / sm[r];
            ctx[((size_t)(b * T_ + qs + lq + r)) * D_ + h * DH_ + nf * 16 + (lane & 15)] = f2bf(o);
        }
    }
}

// ---------------- orchestration ----------------
extern "C" void kernel_launch(void* const* d_in, const int* in_sizes, int n_in,
                              void* d_out, int out_size, void* d_ws, size_t ws_size,
                              hipStream_t stream)
{
    const float* x   = (const float*)d_in[0];
    const float* Wq  = (const float*)d_in[1];
    const float* bq  = (const float*)d_in[2];
    const float* Wk  = (const float*)d_in[3];
    const float* bk  = (const float*)d_in[4];
    const float* Wv  = (const float*)d_in[5];
    const float* bv  = (const float*)d_in[6];
    const float* Wo  = (const float*)d_in[7];
    const float* bo  = (const float*)d_in[8];
    const float* W1  = (const float*)d_in[9];
    const float* b1  = (const float*)d_in[10];
    const float* W2  = (const float*)d_in[11];
    const float* b2  = (const float*)d_in[12];
    const float* g1  = (const float*)d_in[13];
    const float* be1 = (const float*)d_in[14];
    const float* g2  = (const float*)d_in[15];
    const float* be2 = (const float*)d_in[16];
    float* out = (float*)d_out;

    // workspace layout (elements):
    // wqkv_t [2304][768] bf16, wo_t, w1_t, w2_t | hbuf | qbuf | x2 f32 | kbuf | vtb | ffb over kbuf..
    unsigned short* wqkv_t = (unsigned short*)d_ws;        // 3 x [768][768]
    unsigned short* wo_t = wqkv_t + 3 * 589824;
    unsigned short* w1_t = wo_t + 589824;                  // [3072][768]
    unsigned short* w2_t = w1_t + 2359296;                 // [768][3072]
    unsigned short* hbuf = w2_t + 2359296;                 // h1, later ctx
    unsigned short* qbuf = hbuf + 6291456;                 // q, later h2
    float* x2 = (float*)(qbuf + 6291456);                  // fp32 [8192][768]
    unsigned short* kbuf = (unsigned short*)(x2 + 6291456);
    unsigned short* vtb  = kbuf + 6291456;                 // [4][768][2048]
    unsigned short* ffb  = kbuf;                           // [8192][3072] over k/vt/extra

    dim3 tb(32, 8);
    tcvt4_kernel<<<dim3(24, 24, 4), tb, 0, stream>>>(Wq, Wk, Wv, Wo, wqkv_t);
    tcvt_kernel<<<dim3(96, 24), tb, 0, stream>>>(W1, w1_t, 768, 3072);
    tcvt_kernel<<<dim3(24, 96), tb, 0, stream>>>(W2, w2_t, 3072, 768);

    ln_kernel<<<8192, 256, 0, stream>>>(x, g1, be1, hbuf);

    // fused QKV: N = 2304, routes Q->qbuf, K->kbuf, V->vtb(transposed)
    gemm512<4><<<64 * 18, 512, 0, stream>>>(
        hbuf, wqkv_t, bq, bk, bv, nullptr, qbuf, kbuf, vtb, 2304, 768, 18);

    attn_kernel<<<1536, 256, 0, stream>>>(qbuf, kbuf, vtb, hbuf);   // ctx -> hbuf

    gemm512<3><<<64 * 6, 512, 0, stream>>>(
        hbuf, wo_t, bo, nullptr, nullptr, x, x2, nullptr, nullptr, 768, 768, 6);

    ln_kernel<<<8192, 256, 0, stream>>>(x2, g2, be2, qbuf);         // h2 -> qbuf

    gemm512<2><<<64 * 24, 512, 0, stream>>>(
        qbuf, w1_t, b1, nullptr, nullptr, nullptr, ffb, nullptr, nullptr, 3072, 768, 24);

    gemm512<3><<<64 * 6, 512, 0, stream>>>(
        ffb, w2_t, b2, nullptr, nullptr, x2, out, nullptr, nullptr, 768, 3072, 6);
}